// Round 3
// baseline (759.598 us; speedup 1.0000x reference)
//
#include <hip/hip_runtime.h>
#include <hip/hip_bf16.h>

#define Bz 16
#define Tz 256
#define T2z 16
#define Hz 256
#define DRz 64
#define DEPTHz 8
#define ROWSz (Bz * (Tz + 2))   // 4128 rows in flat h/c tables
#define NODESz (Bz * Tz)        // 4096 tree nodes
#define NB 8                    // nodes per level-kernel block

typedef short bf16x8 __attribute__((ext_vector_type(8)));
typedef float f32x4 __attribute__((ext_vector_type(4)));

__device__ __forceinline__ float sigmoid_(float x) { return 1.0f / (1.0f + __expf(-x)); }
__device__ __forceinline__ float tanh_(float x) {
    float e = __expf(2.0f * x);
    return 1.0f - 2.0f / (e + 1.0f);
}
__device__ __forceinline__ short f2b(float f) {
    __hip_bfloat16 h = __float2bfloat16(f);
    return *(short*)&h;
}
__device__ __forceinline__ float b2f(short s) {
    return __uint_as_float(((unsigned)(unsigned short)s) << 16);
}
__device__ __forceinline__ void gload16(const short* g, short* l) {
    __builtin_amdgcn_global_load_lds((const __attribute__((address_space(1))) void*)g,
                                     (__attribute__((address_space(3))) void*)l, 16, 0, 0);
}

// C[M,N] = A[M,K]_bf16 @ BT[N,K]^T (+bias). Output fp32 (C) or bf16 (Cb).
__global__ __launch_bounds__(256) void bgemm_k(const short* __restrict__ A,
                                               const short* __restrict__ BT,
                                               const float* __restrict__ bias,
                                               float* __restrict__ C,
                                               short* __restrict__ Cb,
                                               int K, int N) {
    __shared__ short As[64 * 32];
    __shared__ short Bs[64 * 32];
    const int tid = threadIdx.x;
    const int w = tid >> 6, lane = tid & 63;
    const int m0 = blockIdx.y * 64, n0 = blockIdx.x * 64;
    const int r16 = lane & 15, q = lane >> 4;
    f32x4 acc[4] = {};
    const short* ga = A + (size_t)(m0 + w * 16 + (lane >> 2)) * K + (lane & 3) * 8;
    const short* gb = BT + (size_t)(n0 + w * 16 + (lane >> 2)) * K + (lane & 3) * 8;
    short* la = As + w * 512;
    short* lb = Bs + w * 512;
    for (int kt = 0; kt < K; kt += 32) {
        __syncthreads();
        gload16(ga + kt, la);
        gload16(gb + kt, lb);
        __syncthreads();
        bf16x8 bfrag = *(const bf16x8*)&Bs[(w * 16 + r16) * 32 + q * 8];
#pragma unroll
        for (int i = 0; i < 4; i++) {
            bf16x8 afrag = *(const bf16x8*)&As[(i * 16 + r16) * 32 + q * 8];
            acc[i] = __builtin_amdgcn_mfma_f32_16x16x32_bf16(afrag, bfrag, acc[i], 0, 0, 0);
        }
    }
    const int col = n0 + w * 16 + r16;
    const float bv = bias ? bias[col] : 0.0f;
#pragma unroll
    for (int i = 0; i < 4; i++)
#pragma unroll
        for (int r = 0; r < 4; r++) {
            const size_t o = (size_t)(m0 + i * 16 + q * 4 + r) * N + col;
            if (Cb) Cb[o] = f2b(acc[i][r] + bv);
            else    C[o]  = acc[i][r] + bv;
        }
}

// One-time weight prep: bf16 transposes + composed proj bias [0 | b_hf].
__global__ __launch_bounds__(256) void prep_w_k(const float* __restrict__ Wx,
                                                const float* __restrict__ Whp,
                                                const float* __restrict__ Whf,
                                                const float* __restrict__ bhf,
                                                const float* __restrict__ Whiou,
                                                const float* __restrict__ Wdep,
                                                short* __restrict__ WTx,
                                                short* __restrict__ WTcat,
                                                short* __restrict__ WThiou,
                                                short* __restrict__ WTdep,
                                                float* __restrict__ bias_cat) {
    int e = blockIdx.x * 256 + threadIdx.x;
    if (e < 262144) { int n = e >> 8, k = e & 255; WTx[e] = f2b(Wx[k * 1024 + n]); return; }
    e -= 262144;
    if (e < 131072) {
        int n = e >> 8, k = e & 255;
        WTcat[e] = f2b((n < 256) ? Whp[k * 256 + n] : Whf[k * 256 + (n - 256)]);
        return;
    }
    e -= 131072;
    if (e < 196608) { int n = e >> 8, k = e & 255; WThiou[e] = f2b(Whiou[k * 768 + n]); return; }
    e -= 196608;
    if (e < 16384) { int n = e >> 6, k = e & 63; WTdep[e] = f2b(Wdep[k * 256 + n]); return; }
    e -= 16384;
    if (e < 512) bias_cat[e] = (e < 256) ? 0.0f : bhf[e - 256];
}

__global__ __launch_bounds__(256) void cast_k(const float* __restrict__ s,
                                              short* __restrict__ d, int n4) {
    int i = blockIdx.x * 256 + threadIdx.x;
    if (i < n4) {
        float4 v = ((const float4*)s)[i];
        short4 o; o.x = f2b(v.x); o.y = f2b(v.y); o.z = f2b(v.z); o.w = f2b(v.w);
        ((short4*)d)[i] = o;
    }
}

// Level-0 state for BOTH ping-pong buffers: h=c=0, proj = [0 | b_hf].
__global__ __launch_bounds__(256) void init_k(const float* __restrict__ bhf,
                                              short* rnh0, short* rnh1,
                                              float* rnc0, float* rnc1,
                                              short* pj0, short* pj1) {
    const int r = blockIdx.x, tid = threadIdx.x;
    const size_t o = (size_t)r * 256 + tid;
    rnh0[o] = 0; rnh1[o] = 0; rnc0[o] = 0.0f; rnc1[o] = 0.0f;
    const size_t p = (size_t)r * 512 + tid;
    pj0[p] = 0; pj1[p] = 0;
    const short bh = f2b(bhf[tid]);
    pj0[p + 256] = bh; pj1[p + 256] = bh;
}

// One fused kernel per tree level. Block = 8 consecutive nodes (same batch b).
// Phases: logits -> softmax -> gather/aggregate -> MFMA h_iou -> gates+renorm
//         -> MFMA proj (next level). Double-buffered tables (read prev, write next).
__global__ __launch_bounds__(256, 2) void level_k(const int* __restrict__ trees,
                                                  const float* __restrict__ cmask,
                                                  const short* __restrict__ rnh_i,
                                                  const float* __restrict__ rnc_i,
                                                  const short* __restrict__ proj_i,
                                                  const short* __restrict__ dp_b,
                                                  const float* __restrict__ attnv,
                                                  const float* __restrict__ xiouf,
                                                  const short* __restrict__ WThiou,
                                                  const float* __restrict__ b_hiou,
                                                  const short* __restrict__ WTcat,
                                                  const float* __restrict__ biascat,
                                                  short* __restrict__ rnh_o,
                                                  float* __restrict__ rnc_o,
                                                  short* __restrict__ proj_o,
                                                  float* __restrict__ out,
                                                  int last) {
    __shared__ int   sidx[128];
    __shared__ float smask[128];
    __shared__ float slog[128];
    __shared__ float sa[128];
    __shared__ float xfL[16 * 256];
    __shared__ float fsumL[NB * 256];
    __shared__ float hiouL[NB * 768];
    __shared__ short hjt[16 * 264];   // A-tile (rows 8..15 zero)
    __shared__ short ht2[16 * 264];   // renormed h A-tile (rows 8..15 zero)

    const int tid = threadIdx.x;
    const int w = tid >> 6, lane = tid & 63;
    const int lane4 = lane * 4;
    const int r16 = lane & 15, q = lane >> 4;
    const int node0 = blockIdx.x * NB;
    const int b = node0 >> 8, t0 = node0 & 255;

    // ---- Phase A: indices, masks, x_f slab, pad-row zeroing ----
    if (tid < 128) {
        sidx[tid] = trees[node0 * 16 + tid];
        smask[tid] = cmask[node0 * 16 + tid];
        slog[tid] = -1e30f;
    }
    for (int i = tid; i < 1024; i += 256)   // x_f rows b*256+j (j<16), cols 768..1023
        ((float4*)xfL)[i] = ((const float4*)xiouf)[(size_t)(b * 256 + (i >> 6)) * 256 + 192 + (i & 63)];
    for (int i = tid; i < 1056; i += 256) { ((int*)hjt)[1056 + i] = 0; ((int*)ht2)[1056 + i] = 0; }
    __syncthreads();

    // ---- Phase B: logits. Wave w: pairs p = w*32 .. w*32+31 (node = p>>4, j = p&15) ----
    {
        const float4 av = *(const float4*)(attnv + lane4);
        for (int i = 0; i < 32; i++) {
            const int p = w * 32 + i;
            if (smask[p] != 0.0f) {
                const int idx = sidx[p];
                short4 ph = *(const short4*)(proj_i + (size_t)idx * 512 + lane4);
                short4 dv = *(const short4*)(dp_b + ((size_t)node0 * 16 + p) * 256 + lane4);
                float s = tanh_(b2f(ph.x) + b2f(dv.x)) * av.x
                        + tanh_(b2f(ph.y) + b2f(dv.y)) * av.y
                        + tanh_(b2f(ph.z) + b2f(dv.z)) * av.z
                        + tanh_(b2f(ph.w) + b2f(dv.w)) * av.w;
#pragma unroll
                for (int off = 32; off > 0; off >>= 1) s += __shfl_down(s, off);
                if (lane == 0) slog[p] = s;
            }
        }
    }
    __syncthreads();

    // ---- Phase C: per-node softmax over 16 children ----
    if (tid < NB) {
        float mx = -1e30f;
#pragma unroll
        for (int j = 0; j < 16; j++) mx = fmaxf(mx, slog[tid * 16 + j]);
        float e[16], den = 0.0f;
#pragma unroll
        for (int j = 0; j < 16; j++) { e[j] = __expf(slog[tid * 16 + j] - mx); den += e[j]; }
        const float inv = 1.0f / den;
#pragma unroll
        for (int j = 0; j < 16; j++) sa[tid * 16 + j] = e[j] * inv;
    }
    __syncthreads();

    // ---- Phase D: gather/aggregate h_j and fsum. Wave w: nodes 2w, 2w+1 ----
    for (int nn = 0; nn < 2; nn++) {
        const int nl = w * 2 + nn;
        float hj[4] = {}, fs[4] = {};
#pragma unroll
        for (int j = 0; j < 16; j++) {
            const int p = nl * 16 + j;
            if (smask[p] != 0.0f) {  // exact: masked terms are x mask in ref
                const int idx = sidx[p];
                const float aj = sa[p];
                short4 chs = *(const short4*)(rnh_i + (size_t)idx * 256 + lane4);
                float4 ccv = *(const float4*)(rnc_i + (size_t)idx * 256 + lane4);
                short4 pfs = *(const short4*)(proj_i + (size_t)idx * 512 + 256 + lane4);
                float4 xfv = *(const float4*)(xfL + j * 256 + lane4);
                hj[0] = fmaf(b2f(chs.x), aj, hj[0]);
                hj[1] = fmaf(b2f(chs.y), aj, hj[1]);
                hj[2] = fmaf(b2f(chs.z), aj, hj[2]);
                hj[3] = fmaf(b2f(chs.w), aj, hj[3]);
                fs[0] = fmaf(sigmoid_(xfv.x + b2f(pfs.x)), ccv.x, fs[0]);
                fs[1] = fmaf(sigmoid_(xfv.y + b2f(pfs.y)), ccv.y, fs[1]);
                fs[2] = fmaf(sigmoid_(xfv.z + b2f(pfs.z)), ccv.z, fs[2]);
                fs[3] = fmaf(sigmoid_(xfv.w + b2f(pfs.w)), ccv.w, fs[3]);
            }
        }
        short4 o; o.x = f2b(hj[0]); o.y = f2b(hj[1]); o.z = f2b(hj[2]); o.w = f2b(hj[3]);
        *(short4*)(hjt + nl * 264 + lane4) = o;
        *(float4*)(fsumL + nl * 256 + lane4) = make_float4(fs[0], fs[1], fs[2], fs[3]);
    }
    __syncthreads();

    // ---- Phase F: h_iou = hj(8x256) @ W_hiou(256x768) via MFMA (M=16 frags) ----
    {
        f32x4 acc[12] = {};
        for (int kt = 0; kt < 8; kt++) {
            bf16x8 af = *(const bf16x8*)(hjt + r16 * 264 + kt * 32 + q * 8);
#pragma unroll
            for (int f = 0; f < 12; f++) {
                const int nf = w * 12 + f;
                bf16x8 bf = *(const bf16x8*)(WThiou + (size_t)(nf * 16 + r16) * 256 + kt * 32 + q * 8);
                acc[f] = __builtin_amdgcn_mfma_f32_16x16x32_bf16(af, bf, acc[f], 0, 0, 0);
            }
        }
#pragma unroll
        for (int f = 0; f < 12; f++)
#pragma unroll
            for (int r = 0; r < 4; r++) {
                const int m = q * 4 + r;
                if (m < NB) hiouL[m * 768 + (w * 12 + f) * 16 + r16] = acc[f][r];
            }
    }
    __syncthreads();

    // ---- Phase G: gates + c/h update (+ renorm & table writes if !last) ----
    {
        const int nl = tid >> 5;
        const int el0 = (tid & 31) * 8;
        const int gnode = node0 + nl;
        const float* xr = xiouf + (size_t)gnode * 1024;
        float hn[8], cn[8], hs = 0.0f, cs = 0.0f;
#pragma unroll
        for (int u = 0; u < 8; u += 4) {
            float4 xi = *(const float4*)(xr + el0 + u);
            float4 xo = *(const float4*)(xr + 256 + el0 + u);
            float4 xu = *(const float4*)(xr + 512 + el0 + u);
            float4 bi = *(const float4*)(b_hiou + el0 + u);
            float4 bo = *(const float4*)(b_hiou + 256 + el0 + u);
            float4 bu = *(const float4*)(b_hiou + 512 + el0 + u);
            float4 hi = *(const float4*)(hiouL + nl * 768 + el0 + u);
            float4 ho = *(const float4*)(hiouL + nl * 768 + 256 + el0 + u);
            float4 hu = *(const float4*)(hiouL + nl * 768 + 512 + el0 + u);
            float4 fv = *(const float4*)(fsumL + nl * 256 + el0 + u);
            float igv[4] = { xi.x + hi.x + bi.x, xi.y + hi.y + bi.y, xi.z + hi.z + bi.z, xi.w + hi.w + bi.w };
            float ogv[4] = { xo.x + ho.x + bo.x, xo.y + ho.y + bo.y, xo.z + ho.z + bo.z, xo.w + ho.w + bo.w };
            float ugv[4] = { xu.x + hu.x + bu.x, xu.y + hu.y + bu.y, xu.z + hu.z + bu.z, xu.w + hu.w + bu.w };
            float fvv[4] = { fv.x, fv.y, fv.z, fv.w };
#pragma unroll
            for (int z = 0; z < 4; z++) {
                const float c = fmaf(sigmoid_(igv[z]), tanh_(ugv[z]), fvv[z]);
                const float h = sigmoid_(ogv[z]) * tanh_(c);
                hn[u + z] = h; cn[u + z] = c;
                hs = fmaf(h, h, hs); cs = fmaf(c, c, cs);
            }
        }
        if (last) {
#pragma unroll
            for (int u = 0; u < 8; u += 4)
                *(float4*)(out + (size_t)gnode * 256 + el0 + u) =
                    make_float4(hn[u], hn[u + 1], hn[u + 2], hn[u + 3]);
            return;  // uniform across grid
        }
#pragma unroll
        for (int off = 16; off > 0; off >>= 1) {
            hs += __shfl_xor(hs, off);
            cs += __shfl_xor(cs, off);
        }
        const float nh = sqrtf(hs), ncn = sqrtf(cs);
        const float sh = nh > 2.0f ? 2.0f / nh : 1.0f;
        const float sc = ncn > 2.0f ? 2.0f / ncn : 1.0f;
        const size_t grow = (size_t)b * (Tz + 2) + t0 + nl + 2;
        short hb[8];
#pragma unroll
        for (int u = 0; u < 8; u += 4) {
            *(float4*)(rnc_o + grow * 256 + el0 + u) =
                make_float4(cn[u] * sc, cn[u + 1] * sc, cn[u + 2] * sc, cn[u + 3] * sc);
#pragma unroll
            for (int z = 0; z < 4; z++) hb[u + z] = f2b(hn[u + z] * sh);
        }
        *(short4*)(rnh_o + grow * 256 + el0) = *(short4*)&hb[0];
        *(short4*)(rnh_o + grow * 256 + el0 + 4) = *(short4*)&hb[4];
        *(short4*)(ht2 + nl * 264 + el0) = *(short4*)&hb[0];
        *(short4*)(ht2 + nl * 264 + el0 + 4) = *(short4*)&hb[4];
    }
    __syncthreads();

    // ---- Phase H: proj = rn_h(8x256) @ [W_hproj|W_hf](256x512) + biascat ----
    {
        f32x4 acc[8] = {};
        for (int kt = 0; kt < 8; kt++) {
            bf16x8 af = *(const bf16x8*)(ht2 + r16 * 264 + kt * 32 + q * 8);
#pragma unroll
            for (int f = 0; f < 8; f++) {
                const int nf = w * 8 + f;
                bf16x8 bf = *(const bf16x8*)(WTcat + (size_t)(nf * 16 + r16) * 256 + kt * 32 + q * 8);
                acc[f] = __builtin_amdgcn_mfma_f32_16x16x32_bf16(af, bf, acc[f], 0, 0, 0);
            }
        }
#pragma unroll
        for (int f = 0; f < 8; f++) {
            const int col = (w * 8 + f) * 16 + r16;
            const float bc = biascat[col];
#pragma unroll
            for (int r = 0; r < 4; r++) {
                const int m = q * 4 + r;
                if (m < NB) {
                    const size_t grow = (size_t)b * (Tz + 2) + t0 + m + 2;
                    proj_o[grow * 512 + col] = f2b(acc[f][r] + bc);
                }
            }
        }
    }
}

extern "C" void kernel_launch(void* const* d_in, const int* in_sizes, int n_in,
                              void* d_out, int out_size, void* d_ws, size_t ws_size,
                              hipStream_t stream) {
    const float* tok     = (const float*)d_in[0];
    const int*   trees   = (const int*)d_in[1];
    const float* cmask   = (const float*)d_in[2];
    const float* cdep    = (const float*)d_in[4];
    const float* W_xiouf = (const float*)d_in[5];
    const float* b_xiouf = (const float*)d_in[6];
    const float* W_hiou  = (const float*)d_in[7];
    const float* b_hiou  = (const float*)d_in[8];
    const float* W_hf    = (const float*)d_in[9];
    const float* b_hf    = (const float*)d_in[10];
    const float* W_dep   = (const float*)d_in[11];
    const float* W_hp    = (const float*)d_in[12];
    const float* W_attnv = (const float*)d_in[13];
    float* out = (float*)d_out;

    char* p = (char*)d_ws;
    auto alloc = [&](size_t bytes) { char* q = p; p += (bytes + 255) & ~255ull; return q; };
    short* rnh[2]; float* rnc[2]; short* pj[2];
    rnh[0] = (short*)alloc((size_t)ROWSz * 256 * 2);
    rnh[1] = (short*)alloc((size_t)ROWSz * 256 * 2);
    rnc[0] = (float*)alloc((size_t)ROWSz * 256 * 4);
    rnc[1] = (float*)alloc((size_t)ROWSz * 256 * 4);
    pj[0]  = (short*)alloc((size_t)ROWSz * 512 * 2);
    pj[1]  = (short*)alloc((size_t)ROWSz * 512 * 2);
    short* dp_b   = (short*)alloc((size_t)NODESz * 16 * 256 * 2);  // 33.5 MB
    float* x_iouf = (float*)alloc((size_t)NODESz * 1024 * 4);      // 16.8 MB
    short* tok_b  = (short*)alloc((size_t)NODESz * 256 * 2);
    short* cdep_b = (short*)alloc((size_t)NODESz * 16 * 64 * 2);
    short* WTx    = (short*)alloc(262144 * 2);
    short* WTcat  = (short*)alloc(131072 * 2);
    short* WThiou = (short*)alloc(196608 * 2);
    short* WTdep  = (short*)alloc(16384 * 2);
    float* biascat= (float*)alloc(512 * 4);

    prep_w_k<<<2370, 256, 0, stream>>>(W_xiouf, W_hp, W_hf, b_hf, W_hiou, W_dep,
                                       WTx, WTcat, WThiou, WTdep, biascat);
    cast_k<<<1024, 256, 0, stream>>>(tok, tok_b, 262144);
    cast_k<<<4096, 256, 0, stream>>>(cdep, cdep_b, 1048576);
    init_k<<<ROWSz, 256, 0, stream>>>(b_hf, rnh[0], rnh[1], rnc[0], rnc[1], pj[0], pj[1]);

    // Hoisted loop-invariant GEMMs
    bgemm_k<<<dim3(16, 64), 256, 0, stream>>>(tok_b, WTx, b_xiouf, x_iouf, nullptr, 256, 1024);
    bgemm_k<<<dim3(4, 1024), 256, 0, stream>>>(cdep_b, WTdep, nullptr, nullptr, dp_b, 64, 256);

    for (int lvl = 0; lvl < DEPTHz; lvl++) {
        const int pi = lvl & 1;
        level_k<<<NODESz / NB, 256, 0, stream>>>(trees, cmask,
                                                 rnh[pi], rnc[pi], pj[pi], dp_b,
                                                 W_attnv, x_iouf, WThiou, b_hiou,
                                                 WTcat, biascat,
                                                 rnh[1 - pi], rnc[1 - pi], pj[1 - pi],
                                                 out, lvl == DEPTHz - 1);
    }
}

// Round 4
// 584.487 us; speedup vs baseline: 1.2996x; 1.2996x over previous
//
#include <hip/hip_runtime.h>
#include <hip/hip_bf16.h>

#define Bz 16
#define Tz 256
#define T2z 16
#define Hz 256
#define DRz 64
#define DEPTHz 8
#define ROWSz (Bz * (Tz + 2))   // 4128 rows in flat h/c tables
#define NODESz (Bz * Tz)        // 4096 tree nodes

typedef short bf16x8 __attribute__((ext_vector_type(8)));
typedef float f32x4 __attribute__((ext_vector_type(4)));

__device__ __forceinline__ float sigmoid_(float x) { return 1.0f / (1.0f + __expf(-x)); }
__device__ __forceinline__ float tanh_(float x) {
    float e = __expf(2.0f * x);
    return 1.0f - 2.0f / (e + 1.0f);
}
__device__ __forceinline__ short f2b(float f) {
    __hip_bfloat16 h = __float2bfloat16(f);
    return *(short*)&h;
}
__device__ __forceinline__ float b2f(short s) {
    return __uint_as_float(((unsigned)(unsigned short)s) << 16);
}
__device__ __forceinline__ void gload16(const short* g, short* l) {
    __builtin_amdgcn_global_load_lds((const __attribute__((address_space(1))) void*)g,
                                     (__attribute__((address_space(3))) void*)l, 16, 0, 0);
}

// C[M,N] = A[M,K]_bf16 @ BT[N,K]^T (+bias). Output fp32 (C) or bf16 (Cb).
__global__ __launch_bounds__(256) void bgemm_k(const short* __restrict__ A,
                                               const short* __restrict__ BT,
                                               const float* __restrict__ bias,
                                               float* __restrict__ C,
                                               short* __restrict__ Cb,
                                               int K, int N) {
    __shared__ short As[64 * 32];
    __shared__ short Bs[64 * 32];
    const int tid = threadIdx.x;
    const int w = tid >> 6, lane = tid & 63;
    const int m0 = blockIdx.y * 64, n0 = blockIdx.x * 64;
    const int r16 = lane & 15, q = lane >> 4;
    f32x4 acc[4] = {};
    const short* ga = A + (size_t)(m0 + w * 16 + (lane >> 2)) * K + (lane & 3) * 8;
    const short* gb = BT + (size_t)(n0 + w * 16 + (lane >> 2)) * K + (lane & 3) * 8;
    short* la = As + w * 512;
    short* lb = Bs + w * 512;
    for (int kt = 0; kt < K; kt += 32) {
        __syncthreads();
        gload16(ga + kt, la);
        gload16(gb + kt, lb);
        __syncthreads();
        bf16x8 bfrag = *(const bf16x8*)&Bs[(w * 16 + r16) * 32 + q * 8];
#pragma unroll
        for (int i = 0; i < 4; i++) {
            bf16x8 afrag = *(const bf16x8*)&As[(i * 16 + r16) * 32 + q * 8];
            acc[i] = __builtin_amdgcn_mfma_f32_16x16x32_bf16(afrag, bfrag, acc[i], 0, 0, 0);
        }
    }
    const int col = n0 + w * 16 + r16;
    const float bv = bias ? bias[col] : 0.0f;
#pragma unroll
    for (int i = 0; i < 4; i++)
#pragma unroll
        for (int r = 0; r < 4; r++) {
            const size_t o = (size_t)(m0 + i * 16 + q * 4 + r) * N + col;
            if (Cb) Cb[o] = f2b(acc[i][r] + bv);
            else    C[o]  = acc[i][r] + bv;
        }
}

// One-time weight prep: bf16 transposes + composed proj bias [0 | b_hf].
__global__ __launch_bounds__(256) void prep_w_k(const float* __restrict__ Wx,
                                                const float* __restrict__ Whp,
                                                const float* __restrict__ Whf,
                                                const float* __restrict__ bhf,
                                                const float* __restrict__ Whiou,
                                                const float* __restrict__ Wdep,
                                                short* __restrict__ WTx,
                                                short* __restrict__ WTcat,
                                                short* __restrict__ WThiou,
                                                short* __restrict__ WTdep,
                                                float* __restrict__ bias_cat) {
    int e = blockIdx.x * 256 + threadIdx.x;
    if (e < 262144) { int n = e >> 8, k = e & 255; WTx[e] = f2b(Wx[k * 1024 + n]); return; }
    e -= 262144;
    if (e < 131072) {
        int n = e >> 8, k = e & 255;
        WTcat[e] = f2b((n < 256) ? Whp[k * 256 + n] : Whf[k * 256 + (n - 256)]);
        return;
    }
    e -= 131072;
    if (e < 196608) { int n = e >> 8, k = e & 255; WThiou[e] = f2b(Whiou[k * 768 + n]); return; }
    e -= 196608;
    if (e < 16384) { int n = e >> 6, k = e & 63; WTdep[e] = f2b(Wdep[k * 256 + n]); return; }
    e -= 16384;
    if (e < 512) bias_cat[e] = (e < 256) ? 0.0f : bhf[e - 256];
}

__global__ __launch_bounds__(256) void cast_k(const float* __restrict__ s,
                                              short* __restrict__ d, int n4) {
    int i = blockIdx.x * 256 + threadIdx.x;
    if (i < n4) {
        float4 v = ((const float4*)s)[i];
        short4 o; o.x = f2b(v.x); o.y = f2b(v.y); o.z = f2b(v.z); o.w = f2b(v.w);
        ((short4*)d)[i] = o;
    }
}

// Level-0 state: h=0 (bf16), c=0 (f32), proj = [0 | b_hf] (bf16).
__global__ __launch_bounds__(256) void init_k(const float* __restrict__ bhf,
                                              short* rnh, float* rnc, short* pj) {
    const int r = blockIdx.x, tid = threadIdx.x;
    rnh[(size_t)r * 256 + tid] = 0;
    rnc[(size_t)r * 256 + tid] = 0.0f;
    pj[(size_t)r * 512 + tid] = 0;
    pj[(size_t)r * 512 + 256 + tid] = f2b(bhf[tid]);
}

// Gather stage: one block per node (4096 blocks — max latency-hiding pool).
// logits -> softmax -> aggregate h_j (bf16) and fsum (f32).
__global__ __launch_bounds__(256) void attn_k(const int* __restrict__ trees,
                                              const float* __restrict__ cmask,
                                              const short* __restrict__ rnh,
                                              const float* __restrict__ rnc,
                                              const short* __restrict__ proj,
                                              const short* __restrict__ dp_b,
                                              const float* __restrict__ attnv,
                                              const float* __restrict__ xiouf,
                                              short* __restrict__ hjb,
                                              float* __restrict__ fsum) {
    __shared__ int sidx[16];
    __shared__ float smask[16];
    __shared__ float slog[16];
    const int node = blockIdx.x, tid = threadIdx.x;
    if (tid < 16) {
        sidx[tid] = trees[node * 16 + tid];
        smask[tid] = cmask[node * 16 + tid];
    }
    __syncthreads();
    const int w = tid >> 6, lane = tid & 63;
    const int lane4 = lane * 4;
    const float4 av = *(const float4*)(attnv + lane4);
    for (int jj = 0; jj < 4; jj++) {  // wave w: children 4w..4w+3
        const int j = w * 4 + jj;
        float lg = -1e30f;  // masked: softmax weight exactly 0 (ref adds log(1e-45))
        if (smask[j] != 0.0f) {
            const int idx = sidx[j];
            short4 ph = *(const short4*)(proj + (size_t)idx * 512 + lane4);
            short4 dv = *(const short4*)(dp_b + ((size_t)node * 16 + j) * 256 + lane4);
            float s = tanh_(b2f(ph.x) + b2f(dv.x)) * av.x
                    + tanh_(b2f(ph.y) + b2f(dv.y)) * av.y
                    + tanh_(b2f(ph.z) + b2f(dv.z)) * av.z
                    + tanh_(b2f(ph.w) + b2f(dv.w)) * av.w;
#pragma unroll
            for (int off = 32; off > 0; off >>= 1) s += __shfl_down(s, off);
            lg = s;
        }
        if (lane == 0) slog[j] = lg;
    }
    __syncthreads();
    float mx = slog[0];
#pragma unroll
    for (int j = 1; j < 16; j++) mx = fmaxf(mx, slog[j]);
    float den = 0.0f;
#pragma unroll
    for (int j = 0; j < 16; j++) den += __expf(slog[j] - mx);
    const float inv = 1.0f / den;
    const int b = node >> 8;
    float hjv = 0.0f, fsv = 0.0f;
    for (int j = 0; j < 16; j++) {
        if (smask[j] == 0.0f) continue;  // exact: masked terms are x mask in ref
        const int idx = sidx[j];
        const float aj = __expf(slog[j] - mx) * inv;
        const float chv = b2f(rnh[(size_t)idx * 256 + tid]);
        const float ccv = rnc[(size_t)idx * 256 + tid];
        const float pfv = b2f(proj[(size_t)idx * 512 + 256 + tid]);
        // faithful to reference bug: x_f indexed by child slot j, not node t
        const float xf = xiouf[(size_t)(b * 256 + j) * 1024 + 768 + tid];
        hjv = fmaf(chv, aj, hjv);
        fsv = fmaf(sigmoid_(xf + pfv), ccv, fsv);
    }
    hjb[(size_t)node * 256 + tid] = f2b(hjv);
    fsum[(size_t)node * 256 + tid] = fsv;
}

// Post stage: 16 nodes/block (256 blocks). h_iou MFMA -> gates -> renorm ->
// proj MFMA for next level. Streaming access only; no gathers.
__global__ __launch_bounds__(256, 2) void post_k(const short* __restrict__ hjb,
                                                 const float* __restrict__ fsum,
                                                 const float* __restrict__ xiouf,
                                                 const short* __restrict__ WThiou,
                                                 const float* __restrict__ b_hiou,
                                                 const short* __restrict__ WTcat,
                                                 const float* __restrict__ biascat,
                                                 short* __restrict__ rnh,
                                                 float* __restrict__ rnc,
                                                 short* __restrict__ proj,
                                                 float* __restrict__ out,
                                                 int last) {
    __shared__ short hjA[16 * 264];     // hj A-tile, padded stride
    __shared__ short htA[16 * 264];     // renormed-h A-tile
    __shared__ float hiouL[16 * 768];   // 48 KB
    const int tid = threadIdx.x;
    const int w = tid >> 6, lane = tid & 63;
    const int r16 = lane & 15, q = lane >> 4;
    const int node0 = blockIdx.x * 16;
    const int b = node0 >> 8, t0 = node0 & 255;

    // Phase 1: stage hj tile (16 rows x 256 bf16)
    {
        const int row = tid >> 4, c0 = (tid & 15) * 16;
        *(int4*)(hjA + row * 264 + c0) = *(const int4*)(hjb + (size_t)(node0 + row) * 256 + c0);
        *(int4*)(hjA + row * 264 + c0 + 8) = *(const int4*)(hjb + (size_t)(node0 + row) * 256 + c0 + 8);
    }
    __syncthreads();

    // Phase 2: h_iou = hj(16x256) @ W_hiou -> hiouL (no bias; gates add it)
    {
        for (int f = 0; f < 12; f++) {
            const int nf = w * 12 + f;
            f32x4 acc = {};
#pragma unroll
            for (int kt = 0; kt < 8; kt++) {
                bf16x8 af = *(const bf16x8*)(hjA + r16 * 264 + kt * 32 + q * 8);
                bf16x8 bf = *(const bf16x8*)(WThiou + (size_t)(nf * 16 + r16) * 256 + kt * 32 + q * 8);
                acc = __builtin_amdgcn_mfma_f32_16x16x32_bf16(af, bf, acc, 0, 0, 0);
            }
#pragma unroll
            for (int r = 0; r < 4; r++)
                hiouL[(q * 4 + r) * 768 + nf * 16 + r16] = acc[r];
        }
    }
    __syncthreads();

    // Phase 3: gates + renorm. Thread t: node nl = t>>4, cols e0..e0+15.
    {
        const int nl = tid >> 4, e0 = (tid & 15) * 16;
        const int gnode = node0 + nl;
        const float* xr = xiouf + (size_t)gnode * 1024;
        const float* hl = hiouL + nl * 768;
        float hn[16], cn[16], hs = 0.0f, cs = 0.0f;
#pragma unroll
        for (int u = 0; u < 16; u += 4) {
            float4 xi = *(const float4*)(xr + e0 + u);
            float4 xo = *(const float4*)(xr + 256 + e0 + u);
            float4 xu = *(const float4*)(xr + 512 + e0 + u);
            float4 hi = *(const float4*)(hl + e0 + u);
            float4 ho = *(const float4*)(hl + 256 + e0 + u);
            float4 hu = *(const float4*)(hl + 512 + e0 + u);
            float4 bi = *(const float4*)(b_hiou + e0 + u);
            float4 bo = *(const float4*)(b_hiou + 256 + e0 + u);
            float4 bu = *(const float4*)(b_hiou + 512 + e0 + u);
            float4 fv = *(const float4*)(fsum + (size_t)gnode * 256 + e0 + u);
            float iv[4] = { xi.x + hi.x + bi.x, xi.y + hi.y + bi.y, xi.z + hi.z + bi.z, xi.w + hi.w + bi.w };
            float ov[4] = { xo.x + ho.x + bo.x, xo.y + ho.y + bo.y, xo.z + ho.z + bo.z, xo.w + ho.w + bo.w };
            float uv[4] = { xu.x + hu.x + bu.x, xu.y + hu.y + bu.y, xu.z + hu.z + bu.z, xu.w + hu.w + bu.w };
            float fa[4] = { fv.x, fv.y, fv.z, fv.w };
#pragma unroll
            for (int z = 0; z < 4; z++) {
                const float c = fmaf(sigmoid_(iv[z]), tanh_(uv[z]), fa[z]);
                const float h = sigmoid_(ov[z]) * tanh_(c);
                cn[u + z] = c; hn[u + z] = h;
                hs = fmaf(h, h, hs); cs = fmaf(c, c, cs);
            }
        }
        if (last) {
#pragma unroll
            for (int u = 0; u < 16; u += 4)
                *(float4*)(out + (size_t)gnode * 256 + e0 + u) =
                    make_float4(hn[u], hn[u + 1], hn[u + 2], hn[u + 3]);
            return;  // uniform across grid
        }
        // row-norm across the node's 16 threads (contiguous lane group)
#pragma unroll
        for (int off = 8; off > 0; off >>= 1) {
            hs += __shfl_xor(hs, off);
            cs += __shfl_xor(cs, off);
        }
        const float nh = sqrtf(hs), ncv = sqrtf(cs);
        const float sh = nh > 2.0f ? 2.0f / nh : 1.0f;
        const float sc = ncv > 2.0f ? 2.0f / ncv : 1.0f;
        const size_t grow = (size_t)b * (Tz + 2) + t0 + nl + 2;
        short hb[16];
#pragma unroll
        for (int u = 0; u < 16; u += 4) {
            *(float4*)(rnc + grow * 256 + e0 + u) =
                make_float4(cn[u] * sc, cn[u + 1] * sc, cn[u + 2] * sc, cn[u + 3] * sc);
#pragma unroll
            for (int z = 0; z < 4; z++) hb[u + z] = f2b(hn[u + z] * sh);
        }
#pragma unroll
        for (int u = 0; u < 16; u += 4) {
            *(short4*)(rnh + grow * 256 + e0 + u) = *(short4*)&hb[u];
            *(short4*)(htA + nl * 264 + e0 + u) = *(short4*)&hb[u];
        }
    }
    __syncthreads();

    // Phase 4: proj = rn_h(16x256) @ [W_hproj|W_hf] + [0|b_hf] -> next level
    {
        for (int f = 0; f < 8; f++) {
            const int nf = w * 8 + f;
            f32x4 acc = {};
#pragma unroll
            for (int kt = 0; kt < 8; kt++) {
                bf16x8 af = *(const bf16x8*)(htA + r16 * 264 + kt * 32 + q * 8);
                bf16x8 bf = *(const bf16x8*)(WTcat + (size_t)(nf * 16 + r16) * 256 + kt * 32 + q * 8);
                acc = __builtin_amdgcn_mfma_f32_16x16x32_bf16(af, bf, acc, 0, 0, 0);
            }
            const int col = nf * 16 + r16;
            const float bc = biascat[col];
#pragma unroll
            for (int r = 0; r < 4; r++) {
                const size_t grow = (size_t)b * (Tz + 2) + t0 + q * 4 + r + 2;
                proj[grow * 512 + col] = f2b(acc[r] + bc);
            }
        }
    }
}

extern "C" void kernel_launch(void* const* d_in, const int* in_sizes, int n_in,
                              void* d_out, int out_size, void* d_ws, size_t ws_size,
                              hipStream_t stream) {
    const float* tok     = (const float*)d_in[0];
    const int*   trees   = (const int*)d_in[1];
    const float* cmask   = (const float*)d_in[2];
    const float* cdep    = (const float*)d_in[4];
    const float* W_xiouf = (const float*)d_in[5];
    const float* b_xiouf = (const float*)d_in[6];
    const float* W_hiou  = (const float*)d_in[7];
    const float* b_hiou  = (const float*)d_in[8];
    const float* W_hf    = (const float*)d_in[9];
    const float* b_hf    = (const float*)d_in[10];
    const float* W_dep   = (const float*)d_in[11];
    const float* W_hp    = (const float*)d_in[12];
    const float* W_attnv = (const float*)d_in[13];
    float* out = (float*)d_out;

    char* p = (char*)d_ws;
    auto alloc = [&](size_t bytes) { char* q = p; p += (bytes + 255) & ~255ull; return q; };
    short* rnh    = (short*)alloc((size_t)ROWSz * 256 * 2);
    float* rnc    = (float*)alloc((size_t)ROWSz * 256 * 4);
    short* pj     = (short*)alloc((size_t)ROWSz * 512 * 2);
    short* dp_b   = (short*)alloc((size_t)NODESz * 16 * 256 * 2);  // 33.5 MB
    float* x_iouf = (float*)alloc((size_t)NODESz * 1024 * 4);      // 16.8 MB
    short* hjb    = (short*)alloc((size_t)NODESz * 256 * 2);
    float* fsumb  = (float*)alloc((size_t)NODESz * 256 * 4);
    short* tok_b  = (short*)alloc((size_t)NODESz * 256 * 2);
    short* cdep_b = (short*)alloc((size_t)NODESz * 16 * 64 * 2);
    short* WTx    = (short*)alloc(262144 * 2);
    short* WTcat  = (short*)alloc(131072 * 2);
    short* WThiou = (short*)alloc(196608 * 2);
    short* WTdep  = (short*)alloc(16384 * 2);
    float* biascat= (float*)alloc(512 * 4);

    prep_w_k<<<2370, 256, 0, stream>>>(W_xiouf, W_hp, W_hf, b_hf, W_hiou, W_dep,
                                       WTx, WTcat, WThiou, WTdep, biascat);
    cast_k<<<1024, 256, 0, stream>>>(tok, tok_b, 262144);
    cast_k<<<4096, 256, 0, stream>>>(cdep, cdep_b, 1048576);
    init_k<<<ROWSz, 256, 0, stream>>>(b_hf, rnh, rnc, pj);

    // Hoisted loop-invariant GEMMs
    bgemm_k<<<dim3(16, 64), 256, 0, stream>>>(tok_b, WTx, b_xiouf, x_iouf, nullptr, 256, 1024);
    bgemm_k<<<dim3(4, 1024), 256, 0, stream>>>(cdep_b, WTdep, nullptr, nullptr, dp_b, 64, 256);

    for (int lvl = 0; lvl < DEPTHz; lvl++) {
        attn_k<<<NODESz, 256, 0, stream>>>(trees, cmask, rnh, rnc, pj, dp_b,
                                           W_attnv, x_iouf, hjb, fsumb);
        post_k<<<NODESz / 16, 256, 0, stream>>>(hjb, fsumb, x_iouf,
                                                WThiou, b_hiou, WTcat, biascat,
                                                rnh, rnc, pj, out, lvl == DEPTHz - 1);
    }
}

// Round 5
// 539.671 us; speedup vs baseline: 1.4075x; 1.0830x over previous
//
#include <hip/hip_runtime.h>
#include <hip/hip_bf16.h>

#define Bz 16
#define Tz 256
#define T2z 16
#define Hz 256
#define DRz 64
#define DEPTHz 8
#define ROWSz (Bz * (Tz + 2))   // 4128 rows in flat h/c tables
#define NODESz (Bz * Tz)        // 4096 tree nodes

typedef short bf16x8 __attribute__((ext_vector_type(8)));
typedef float f32x4 __attribute__((ext_vector_type(4)));

__device__ __forceinline__ float sigmoid_(float x) { return 1.0f / (1.0f + __expf(-x)); }
__device__ __forceinline__ float tanh_(float x) {
    float e = __expf(2.0f * x);
    return 1.0f - 2.0f / (e + 1.0f);
}
__device__ __forceinline__ short f2b(float f) {
    __hip_bfloat16 h = __float2bfloat16(f);
    return *(short*)&h;
}
__device__ __forceinline__ float b2f(short s) {
    return __uint_as_float(((unsigned)(unsigned short)s) << 16);
}
__device__ __forceinline__ void gload16(const short* g, short* l) {
    __builtin_amdgcn_global_load_lds((const __attribute__((address_space(1))) void*)g,
                                     (__attribute__((address_space(3))) void*)l, 16, 0, 0);
}

// C[M,N] = A[M,K]_bf16 @ BT[N,K]^T (+bias). Output fp32 (C) or bf16 (Cb).
__global__ __launch_bounds__(256) void bgemm_k(const short* __restrict__ A,
                                               const short* __restrict__ BT,
                                               const float* __restrict__ bias,
                                               float* __restrict__ C,
                                               short* __restrict__ Cb,
                                               int K, int N) {
    __shared__ short As[64 * 32];
    __shared__ short Bs[64 * 32];
    const int tid = threadIdx.x;
    const int w = tid >> 6, lane = tid & 63;
    const int m0 = blockIdx.y * 64, n0 = blockIdx.x * 64;
    const int r16 = lane & 15, q = lane >> 4;
    f32x4 acc[4] = {};
    const short* ga = A + (size_t)(m0 + w * 16 + (lane >> 2)) * K + (lane & 3) * 8;
    const short* gb = BT + (size_t)(n0 + w * 16 + (lane >> 2)) * K + (lane & 3) * 8;
    short* la = As + w * 512;
    short* lb = Bs + w * 512;
    for (int kt = 0; kt < K; kt += 32) {
        __syncthreads();
        gload16(ga + kt, la);
        gload16(gb + kt, lb);
        __syncthreads();
        bf16x8 bfrag = *(const bf16x8*)&Bs[(w * 16 + r16) * 32 + q * 8];
#pragma unroll
        for (int i = 0; i < 4; i++) {
            bf16x8 afrag = *(const bf16x8*)&As[(i * 16 + r16) * 32 + q * 8];
            acc[i] = __builtin_amdgcn_mfma_f32_16x16x32_bf16(afrag, bfrag, acc[i], 0, 0, 0);
        }
    }
    const int col = n0 + w * 16 + r16;
    const float bv = bias ? bias[col] : 0.0f;
#pragma unroll
    for (int i = 0; i < 4; i++)
#pragma unroll
        for (int r = 0; r < 4; r++) {
            const size_t o = (size_t)(m0 + i * 16 + q * 4 + r) * N + col;
            if (Cb) Cb[o] = f2b(acc[i][r] + bv);
            else    C[o]  = acc[i][r] + bv;
        }
}

// One-time weight prep: bf16 transposes + composed proj bias [0 | b_hf].
__global__ __launch_bounds__(256) void prep_w_k(const float* __restrict__ Wx,
                                                const float* __restrict__ Whp,
                                                const float* __restrict__ Whf,
                                                const float* __restrict__ bhf,
                                                const float* __restrict__ Whiou,
                                                const float* __restrict__ Wdep,
                                                short* __restrict__ WTx,
                                                short* __restrict__ WTcat,
                                                short* __restrict__ WThiou,
                                                short* __restrict__ WTdep,
                                                float* __restrict__ bias_cat) {
    int e = blockIdx.x * 256 + threadIdx.x;
    if (e < 262144) { int n = e >> 8, k = e & 255; WTx[e] = f2b(Wx[k * 1024 + n]); return; }
    e -= 262144;
    if (e < 131072) {
        int n = e >> 8, k = e & 255;
        WTcat[e] = f2b((n < 256) ? Whp[k * 256 + n] : Whf[k * 256 + (n - 256)]);
        return;
    }
    e -= 131072;
    if (e < 196608) { int n = e >> 8, k = e & 255; WThiou[e] = f2b(Whiou[k * 768 + n]); return; }
    e -= 196608;
    if (e < 16384) { int n = e >> 6, k = e & 63; WTdep[e] = f2b(Wdep[k * 256 + n]); return; }
    e -= 16384;
    if (e < 512) bias_cat[e] = (e < 256) ? 0.0f : bhf[e - 256];
}

__global__ __launch_bounds__(256) void cast_k(const float* __restrict__ s,
                                              short* __restrict__ d, int n4) {
    int i = blockIdx.x * 256 + threadIdx.x;
    if (i < n4) {
        float4 v = ((const float4*)s)[i];
        short4 o; o.x = f2b(v.x); o.y = f2b(v.y); o.z = f2b(v.z); o.w = f2b(v.w);
        ((short4*)d)[i] = o;
    }
}

// xfb[b*16+j][e] = bf16(x_iouf[(b*256+j)*1024 + 768 + e]); 256 rows.
__global__ __launch_bounds__(256) void cast_xf_k(const float* __restrict__ xiouf,
                                                 short* __restrict__ xfb) {
    const int r = blockIdx.x, tid = threadIdx.x;   // r = b*16+j
    const int b = r >> 4, j = r & 15;
    xfb[r * 256 + tid] = f2b(xiouf[(size_t)(b * 256 + j) * 1024 + 768 + tid]);
}

// Level-0 packed table: [ph=0 | pf=b_hf | rh=0 | cb=0] per row (bf16).
__global__ __launch_bounds__(256) void init_k(const float* __restrict__ bhf,
                                              short* __restrict__ tab) {
    const int r = blockIdx.x, tid = threadIdx.x;
    short* row = tab + (size_t)r * 1024;
    row[tid] = 0;
    row[256 + tid] = f2b(bhf[tid]);
    row[512 + tid] = 0;
    row[768 + tid] = 0;
}

// Gather stage: one block per node (4096 blocks). ONE pass over children with
// online softmax. Wave w handles children 4w..4w+3; lane covers 4 h-elems.
// tab row layout: [ph(0..255) | pf(256..511) | rh(512..767) | cb(768..1023)].
__global__ __launch_bounds__(256) void attn_k(const int* __restrict__ trees,
                                              const float* __restrict__ cmask,
                                              const short* __restrict__ tab,
                                              const short* __restrict__ dp_b,
                                              const float* __restrict__ attnv,
                                              const short* __restrict__ xfb,
                                              short* __restrict__ hjb,
                                              float* __restrict__ fsum) {
    __shared__ int sidx[16];
    __shared__ float smask[16];
    __shared__ short xfL[16 * 256];   // 8 KB
    __shared__ float hjp[4 * 256];    // 4 KB per-wave partials
    __shared__ float fsp[4 * 256];    // 4 KB
    __shared__ float mw[4], dw[4];
    const int node = blockIdx.x, tid = threadIdx.x;
    const int w = tid >> 6, lane = tid & 63;
    const int e0 = lane * 4;
    const int b = node >> 8;
    if (tid < 16) {
        sidx[tid] = trees[node * 16 + tid];
        smask[tid] = cmask[node * 16 + tid];
    }
    // stage the 16 xf rows for this batch (bf16): 512 int4s
    for (int i = tid; i < 512; i += 256)
        ((int4*)xfL)[i] = ((const int4*)(xfb + (size_t)b * 4096))[i];
    __syncthreads();

    const float4 av = *(const float4*)(attnv + e0);
    float m_run = -1e30f, d_run = 0.0f;
    float hj0 = 0.f, hj1 = 0.f, hj2 = 0.f, hj3 = 0.f;
    float fs0 = 0.f, fs1 = 0.f, fs2 = 0.f, fs3 = 0.f;
#pragma unroll
    for (int jj = 0; jj < 4; jj++) {
        const int j = w * 4 + jj;
        if (smask[j] == 0.0f) continue;  // exact: ref multiplies masked terms by 0
        const int idx = sidx[j];
        const short* row = tab + (size_t)idx * 1024;
        short4 ph = *(const short4*)(row + e0);
        short4 dv = *(const short4*)(dp_b + ((size_t)node * 16 + j) * 256 + e0);
        float s = tanh_(b2f(ph.x) + b2f(dv.x)) * av.x
                + tanh_(b2f(ph.y) + b2f(dv.y)) * av.y
                + tanh_(b2f(ph.z) + b2f(dv.z)) * av.z
                + tanh_(b2f(ph.w) + b2f(dv.w)) * av.w;
#pragma unroll
        for (int off = 32; off > 0; off >>= 1) s += __shfl_xor(s, off);
        float wt;
        if (s > m_run) {  // wave-uniform branch
            const float sc = __expf(m_run - s);
            d_run = fmaf(d_run, sc, 1.0f);
            hj0 *= sc; hj1 *= sc; hj2 *= sc; hj3 *= sc;
            m_run = s; wt = 1.0f;
        } else {
            wt = __expf(s - m_run);
            d_run += wt;
        }
        short4 rh = *(const short4*)(row + 512 + e0);
        short4 cb = *(const short4*)(row + 768 + e0);
        short4 pf = *(const short4*)(row + 256 + e0);
        short4 xf = *(const short4*)(xfL + j * 256 + e0);
        hj0 = fmaf(b2f(rh.x), wt, hj0);
        hj1 = fmaf(b2f(rh.y), wt, hj1);
        hj2 = fmaf(b2f(rh.z), wt, hj2);
        hj3 = fmaf(b2f(rh.w), wt, hj3);
        fs0 = fmaf(sigmoid_(b2f(xf.x) + b2f(pf.x)), b2f(cb.x), fs0);
        fs1 = fmaf(sigmoid_(b2f(xf.y) + b2f(pf.y)), b2f(cb.y), fs1);
        fs2 = fmaf(sigmoid_(b2f(xf.z) + b2f(pf.z)), b2f(cb.z), fs2);
        fs3 = fmaf(sigmoid_(b2f(xf.w) + b2f(pf.w)), b2f(cb.w), fs3);
    }
    *(float4*)(hjp + w * 256 + e0) = make_float4(hj0, hj1, hj2, hj3);
    *(float4*)(fsp + w * 256 + e0) = make_float4(fs0, fs1, fs2, fs3);
    if (lane == 0) { mw[w] = m_run; dw[w] = d_run; }
    __syncthreads();
    // cross-wave combine; thread tid = h-element
    const float m = fmaxf(fmaxf(mw[0], mw[1]), fmaxf(mw[2], mw[3]));
    float D = 0.f, hv = 0.f, fv = 0.f;
#pragma unroll
    for (int ww = 0; ww < 4; ww++) {
        const float sc = __expf(mw[ww] - m);
        D = fmaf(dw[ww], sc, D);
        hv = fmaf(hjp[ww * 256 + tid], sc, hv);
        fv += fsp[ww * 256 + tid];
    }
    const float inv = (D > 0.0f) ? 1.0f / D : 0.0f;  // all-masked: hj = 0
    hjb[(size_t)node * 256 + tid] = f2b(hv * inv);
    fsum[(size_t)node * 256 + tid] = fv;
}

// Post stage: 16 nodes/block (256 blocks). h_iou MFMA -> gates -> renorm ->
// proj MFMA; writes the packed tab row for the next level.
__global__ __launch_bounds__(256, 2) void post_k(const short* __restrict__ hjb,
                                                 const float* __restrict__ fsum,
                                                 const float* __restrict__ xiouf,
                                                 const short* __restrict__ WThiou,
                                                 const float* __restrict__ b_hiou,
                                                 const short* __restrict__ WTcat,
                                                 const float* __restrict__ biascat,
                                                 short* __restrict__ tab,
                                                 float* __restrict__ out,
                                                 int last) {
    __shared__ short hjA[16 * 264];
    __shared__ short htA[16 * 264];
    __shared__ float hiouL[16 * 768];   // 48 KB
    const int tid = threadIdx.x;
    const int w = tid >> 6, lane = tid & 63;
    const int r16 = lane & 15, q = lane >> 4;
    const int node0 = blockIdx.x * 16;
    const int b = node0 >> 8, t0 = node0 & 255;

    // Phase 1: stage hj tile (16 rows x 256 bf16)
    {
        const int row = tid >> 4, c0 = (tid & 15) * 16;
        *(int4*)(hjA + row * 264 + c0) = *(const int4*)(hjb + (size_t)(node0 + row) * 256 + c0);
        *(int4*)(hjA + row * 264 + c0 + 8) = *(const int4*)(hjb + (size_t)(node0 + row) * 256 + c0 + 8);
    }
    __syncthreads();

    // Phase 2: h_iou = hj(16x256) @ W_hiou -> hiouL (bias added in gates)
    for (int f = 0; f < 12; f++) {
        const int nf = w * 12 + f;
        f32x4 acc = {};
#pragma unroll
        for (int kt = 0; kt < 8; kt++) {
            bf16x8 af = *(const bf16x8*)(hjA + r16 * 264 + kt * 32 + q * 8);
            bf16x8 bf = *(const bf16x8*)(WThiou + (size_t)(nf * 16 + r16) * 256 + kt * 32 + q * 8);
            acc = __builtin_amdgcn_mfma_f32_16x16x32_bf16(af, bf, acc, 0, 0, 0);
        }
#pragma unroll
        for (int r = 0; r < 4; r++)
            hiouL[(q * 4 + r) * 768 + nf * 16 + r16] = acc[r];
    }
    __syncthreads();

    // Phase 3: gates + renorm. Thread t: node nl = t>>4, cols e0..e0+15.
    {
        const int nl = tid >> 4, e0 = (tid & 15) * 16;
        const int gnode = node0 + nl;
        const float* xr = xiouf + (size_t)gnode * 1024;
        const float* hl = hiouL + nl * 768;
        float hn[16], cn[16], hs = 0.0f, cs = 0.0f;
#pragma unroll
        for (int u = 0; u < 16; u += 4) {
            float4 xi = *(const float4*)(xr + e0 + u);
            float4 xo = *(const float4*)(xr + 256 + e0 + u);
            float4 xu = *(const float4*)(xr + 512 + e0 + u);
            float4 hi = *(const float4*)(hl + e0 + u);
            float4 ho = *(const float4*)(hl + 256 + e0 + u);
            float4 hu = *(const float4*)(hl + 512 + e0 + u);
            float4 bi = *(const float4*)(b_hiou + e0 + u);
            float4 bo = *(const float4*)(b_hiou + 256 + e0 + u);
            float4 bu = *(const float4*)(b_hiou + 512 + e0 + u);
            float4 fv = *(const float4*)(fsum + (size_t)gnode * 256 + e0 + u);
            float iv[4] = { xi.x + hi.x + bi.x, xi.y + hi.y + bi.y, xi.z + hi.z + bi.z, xi.w + hi.w + bi.w };
            float ov[4] = { xo.x + ho.x + bo.x, xo.y + ho.y + bo.y, xo.z + ho.z + bo.z, xo.w + ho.w + bo.w };
            float uv[4] = { xu.x + hu.x + bu.x, xu.y + hu.y + bu.y, xu.z + hu.z + bu.z, xu.w + hu.w + bu.w };
            float fa[4] = { fv.x, fv.y, fv.z, fv.w };
#pragma unroll
            for (int z = 0; z < 4; z++) {
                const float c = fmaf(sigmoid_(iv[z]), tanh_(uv[z]), fa[z]);
                const float h = sigmoid_(ov[z]) * tanh_(c);
                cn[u + z] = c; hn[u + z] = h;
                hs = fmaf(h, h, hs); cs = fmaf(c, c, cs);
            }
        }
        if (last) {
#pragma unroll
            for (int u = 0; u < 16; u += 4)
                *(float4*)(out + (size_t)gnode * 256 + e0 + u) =
                    make_float4(hn[u], hn[u + 1], hn[u + 2], hn[u + 3]);
            return;  // uniform across grid
        }
#pragma unroll
        for (int off = 8; off > 0; off >>= 1) {
            hs += __shfl_xor(hs, off);
            cs += __shfl_xor(cs, off);
        }
        const float nh = sqrtf(hs), ncv = sqrtf(cs);
        const float sh = nh > 2.0f ? 2.0f / nh : 1.0f;
        const float sc = ncv > 2.0f ? 2.0f / ncv : 1.0f;
        const size_t grow = (size_t)b * (Tz + 2) + t0 + nl + 2;
        short hb[16], cb[16];
#pragma unroll
        for (int u = 0; u < 16; u++) {
            hb[u] = f2b(hn[u] * sh);
            cb[u] = f2b(cn[u] * sc);
        }
#pragma unroll
        for (int u = 0; u < 16; u += 4) {
            *(short4*)(tab + grow * 1024 + 512 + e0 + u) = *(short4*)&hb[u];
            *(short4*)(tab + grow * 1024 + 768 + e0 + u) = *(short4*)&cb[u];
            *(short4*)(htA + nl * 264 + e0 + u) = *(short4*)&hb[u];
        }
    }
    __syncthreads();

    // Phase 4: [ph|pf] = rn_h(16x256) @ [W_hproj|W_hf] + [0|b_hf] -> tab cols 0..511
    for (int f = 0; f < 8; f++) {
        const int nf = w * 8 + f;
        f32x4 acc = {};
#pragma unroll
        for (int kt = 0; kt < 8; kt++) {
            bf16x8 af = *(const bf16x8*)(htA + r16 * 264 + kt * 32 + q * 8);
            bf16x8 bf = *(const bf16x8*)(WTcat + (size_t)(nf * 16 + r16) * 256 + kt * 32 + q * 8);
            acc = __builtin_amdgcn_mfma_f32_16x16x32_bf16(af, bf, acc, 0, 0, 0);
        }
        const int col = nf * 16 + r16;
        const float bc = biascat[col];
#pragma unroll
        for (int r = 0; r < 4; r++) {
            const size_t grow = (size_t)b * (Tz + 2) + t0 + q * 4 + r + 2;
            tab[grow * 1024 + col] = f2b(acc[r] + bc);
        }
    }
}

extern "C" void kernel_launch(void* const* d_in, const int* in_sizes, int n_in,
                              void* d_out, int out_size, void* d_ws, size_t ws_size,
                              hipStream_t stream) {
    const float* tok     = (const float*)d_in[0];
    const int*   trees   = (const int*)d_in[1];
    const float* cmask   = (const float*)d_in[2];
    const float* cdep    = (const float*)d_in[4];
    const float* W_xiouf = (const float*)d_in[5];
    const float* b_xiouf = (const float*)d_in[6];
    const float* W_hiou  = (const float*)d_in[7];
    const float* b_hiou  = (const float*)d_in[8];
    const float* W_hf    = (const float*)d_in[9];
    const float* b_hf    = (const float*)d_in[10];
    const float* W_dep   = (const float*)d_in[11];
    const float* W_hp    = (const float*)d_in[12];
    const float* W_attnv = (const float*)d_in[13];
    float* out = (float*)d_out;

    char* p = (char*)d_ws;
    auto alloc = [&](size_t bytes) { char* q = p; p += (bytes + 255) & ~255ull; return q; };
    short* tab    = (short*)alloc((size_t)ROWSz * 1024 * 2);       // 8.5 MB packed
    short* dp_b   = (short*)alloc((size_t)NODESz * 16 * 256 * 2);  // 33.5 MB
    float* x_iouf = (float*)alloc((size_t)NODESz * 1024 * 4);      // 16.8 MB
    short* xfb    = (short*)alloc((size_t)Bz * 16 * 256 * 2);      // 128 KB
    short* hjb    = (short*)alloc((size_t)NODESz * 256 * 2);
    float* fsumb  = (float*)alloc((size_t)NODESz * 256 * 4);
    short* tok_b  = (short*)alloc((size_t)NODESz * 256 * 2);
    short* cdep_b = (short*)alloc((size_t)NODESz * 16 * 64 * 2);
    short* WTx    = (short*)alloc(262144 * 2);
    short* WTcat  = (short*)alloc(131072 * 2);
    short* WThiou = (short*)alloc(196608 * 2);
    short* WTdep  = (short*)alloc(16384 * 2);
    float* biascat= (float*)alloc(512 * 4);

    prep_w_k<<<2370, 256, 0, stream>>>(W_xiouf, W_hp, W_hf, b_hf, W_hiou, W_dep,
                                       WTx, WTcat, WThiou, WTdep, biascat);
    cast_k<<<1024, 256, 0, stream>>>(tok, tok_b, 262144);
    cast_k<<<4096, 256, 0, stream>>>(cdep, cdep_b, 1048576);
    init_k<<<ROWSz, 256, 0, stream>>>(b_hf, tab);

    bgemm_k<<<dim3(16, 64), 256, 0, stream>>>(tok_b, WTx, b_xiouf, x_iouf, nullptr, 256, 1024);
    cast_xf_k<<<256, 256, 0, stream>>>(x_iouf, xfb);
    bgemm_k<<<dim3(4, 1024), 256, 0, stream>>>(cdep_b, WTdep, nullptr, nullptr, dp_b, 64, 256);

    for (int lvl = 0; lvl < DEPTHz; lvl++) {
        attn_k<<<NODESz, 256, 0, stream>>>(trees, cmask, tab, dp_b, W_attnv, xfb,
                                           hjb, fsumb);
        post_k<<<NODESz / 16, 256, 0, stream>>>(hjb, fsumb, x_iouf,
                                                WThiou, b_hiou, WTcat, biascat,
                                                tab, out, lvl == DEPTHz - 1);
    }
}